// Round 17
// baseline (158.186 us; speedup 1.0000x reference)
//
#include <hip/hip_runtime.h>
#include <stdint.h>

typedef __attribute__((ext_vector_type(4))) float  f32x4;
typedef __attribute__((ext_vector_type(8))) short  s16x8;
typedef __attribute__((ext_vector_type(4))) short  s16x4;
typedef __attribute__((ext_vector_type(4))) unsigned int u32x4;
typedef __attribute__((ext_vector_type(2))) unsigned int u32x2;

__device__ __forceinline__ unsigned short f2bf(float x) {
  union { float f; unsigned int u; } a; a.f = x;
  unsigned int lsb = (a.u >> 16) & 1u;
  a.u += 0x7fffu + lsb;                    // round-to-nearest-even
  return (unsigned short)(a.u >> 16);
}
__device__ __forceinline__ float bf2f(unsigned short h) {
  union { unsigned int u; float f; } a; a.u = ((unsigned int)h) << 16; return a.f;
}
// HW packed f32->bf16 RNE: lo16 = bf16(a), hi16 = bf16(b). Bit-identical to f2bf.
__device__ __forceinline__ unsigned int cvtpk(float a, float b) {
  unsigned int d;
  asm("v_cvt_pk_bf16_f32 %0, %1, %2" : "=v"(d) : "v"(a), "v"(b));
  return d;
}
__device__ __forceinline__ float bflo_f(unsigned int u) {
  union { unsigned int u; float f; } x; x.u = u << 16; return x.f;
}
__device__ __forceinline__ float bfhi_f(unsigned int u) {
  union { unsigned int u; float f; } x; x.u = u & 0xffff0000u; return x.f;
}
__device__ __forceinline__ s16x8 pk4(unsigned a, unsigned b, unsigned c, unsigned d) {
  union { u32x4 u; s16x8 s; } x;
  u32x4 v = {a, b, c, d}; x.u = v; return x.s;
}

__device__ __forceinline__ void gload_lds16(const void* g, void* s) {
  __builtin_amdgcn_global_load_lds(
      (__attribute__((address_space(1))) void*)g,
      (__attribute__((address_space(3))) void*)s, 16, 0, 0);
}

#define VMCNT(N) asm volatile("s_waitcnt vmcnt(" #N ")" ::: "memory")
#define LGKM0()  asm volatile("s_waitcnt lgkmcnt(0)" ::: "memory")
#define SBAR()   __builtin_amdgcn_s_barrier()
#define SFENCE() __builtin_amdgcn_sched_barrier(0)

// ---------------- K1: Q partials (f32 TN, K-split 4) ----------------
__global__ __launch_bounds__(256) void k_q_part(
    const float* __restrict__ A, const float* __restrict__ Bm,
    float* __restrict__ Qp) {
  __shared__ float As[32][33], Bs[32][33];
  int tid = threadIdx.x;
  int bm = blockIdx.x * 32, bn = blockIdx.y * 32;
  int kbase = blockIdx.z * 256;
  int tr = tid & 31, tq = tid >> 5;
  float acc[4] = {0.f, 0.f, 0.f, 0.f};
  for (int k0 = kbase; k0 < kbase + 256; k0 += 32) {
#pragma unroll
    for (int i = 0; i < 4; i++) {
      int idx = tid + i * 256;
      int r = idx >> 5, c = idx & 31;
      As[r][c] = A[(size_t)(bm + r) * 1024 + k0 + c];
      Bs[r][c] = Bm[(size_t)(bn + r) * 1024 + k0 + c];
    }
    __syncthreads();
#pragma unroll
    for (int kk = 0; kk < 32; kk++) {
      float b = Bs[tr][kk];
#pragma unroll
      for (int i = 0; i < 4; i++) acc[i] += As[tq * 4 + i][kk] * b;
    }
    __syncthreads();
  }
#pragma unroll
  for (int i = 0; i < 4; i++)
    Qp[(size_t)blockIdx.z * 131072 + (size_t)(bm + tq * 4 + i) * 1024 + bn + tr] = acc[i];
}

// ---------------- K2: QW partials (f32 NN, K-split 4) ----------------
__global__ __launch_bounds__(256) void k_qw_part(
    const float* __restrict__ Qp, const float* __restrict__ bq,
    const float* __restrict__ Wk, float* __restrict__ QWp) {
  __shared__ float As[32][33], Bs[32][33];
  int tid = threadIdx.x;
  int bm = blockIdx.x * 32, bn = blockIdx.y * 32;
  int kbase = blockIdx.z * 256;
  int tr = tid & 31, tq = tid >> 5;
  float acc[4] = {0.f, 0.f, 0.f, 0.f};
  for (int k0 = kbase; k0 < kbase + 256; k0 += 32) {
#pragma unroll
    for (int i = 0; i < 4; i++) {
      int idx = tid + i * 256;
      int r = idx >> 5, c = idx & 31;
      size_t qa = (size_t)(bm + r) * 1024 + k0 + c;
      float s = (Qp[qa] + Qp[qa + 131072]) + (Qp[qa + 262144] + Qp[qa + 393216]);
      As[r][c] = s + bq[k0 + c];
      Bs[r][c] = Wk[(size_t)(k0 + r) * 1024 + bn + c];
    }
    __syncthreads();
#pragma unroll
    for (int kk = 0; kk < 32; kk++) {
      float b = Bs[kk][tr];
#pragma unroll
      for (int i = 0; i < 4; i++) acc[i] += As[tq * 4 + i][kk] * b;
    }
    __syncthreads();
  }
#pragma unroll
  for (int i = 0; i < 4; i++)
    QWp[(size_t)blockIdx.z * 131072 + (size_t)(bm + tq * 4 + i) * 1024 + bn + tr] = acc[i];
}

// ---------------- K3: reduce QW partials -> hi/lo split; + convert Wv -> bf16 ----------------
__global__ __launch_bounds__(256) void k_reduce_convert(
    const float* __restrict__ QWp, const float* __restrict__ Wv,
    unsigned short* __restrict__ QWh, unsigned short* __restrict__ QWl,
    unsigned short* __restrict__ Wvh) {
  int bid = blockIdx.x;
  if (bid < 128) {
    int i = bid * 256 + threadIdx.x;        // f32x4 index, 32768 total
    const f32x4* P4 = (const f32x4*)QWp;
    f32x4 a = P4[i], b = P4[i + 32768], c = P4[i + 65536], d = P4[i + 98304];
    f32x4 s;
#pragma unroll
    for (int j = 0; j < 4; j++) s[j] = (a[j] + b[j]) + (c[j] + d[j]);
    unsigned h0 = cvtpk(s[0], s[1]), h1 = cvtpk(s[2], s[3]);
    unsigned l0 = cvtpk(s[0] - bflo_f(h0), s[1] - bfhi_f(h0));
    unsigned l1 = cvtpk(s[2] - bflo_f(h1), s[3] - bfhi_f(h1));
    u32x2 hv = {h0, h1}, lv = {l0, l1};
    ((u32x2*)QWh)[i] = hv;
    ((u32x2*)QWl)[i] = lv;
  } else {
    int i = (bid - 128) * 256 + threadIdx.x;  // f32x4 index, 262144 total
    f32x4 v = ((const f32x4*)Wv)[i];
    u32x2 h;
    h[0] = cvtpk(v[0], v[1]);
    h[1] = cvtpk(v[2], v[3]);
    ((u32x2*)Wvh)[i] = h;
  }
}

// ---------------- K5: fused scores + softmax + ctx ----------------
// Block (b, lh): scores S[64 l][256 r] = QW[lh] @ img[b]^T. B (img) reg-loaded
// f32 COALESCED (8 lanes/row: one wave-inst touches 8 lines, not 32), cvt_pk ->
// bf16 hi/lo LDS (64-B rows, swizzled). Counted vmcnt(5), 3 bufs. Then
// in-register softmax; P -> swizzled LDS; ctx = P @ img[b] (transpose-staged).
__global__ __launch_bounds__(512, 2) void k_fused(
    const unsigned short* __restrict__ QWh, const unsigned short* __restrict__ QWl,
    const float* __restrict__ img, unsigned short* __restrict__ Cp) {
  // bufs 0/40960/81920, each 40 KB: Ah@0 (4K), Al@4096 (4K), Bh@8192 (16K),
  // Bl@24576 (16K). After scores: P@81920 (32K), RMAX@114688, RSUM@115712.
  // ctx bufs 0/16384/32768 (16 KB each) live in buf0/buf1 space.
  __shared__ __attribute__((aligned(16))) char lds[122880];
  int tid = threadIdx.x, l = tid & 63, w = tid >> 6;
  int wm = w >> 2, wn = w & 3;              // 2 x 4 wave grid
  int lr = l & 15, lk8 = l >> 4;
  int sF = (lr >> 1) & 3;
  int rh = lk8 * 4;
  int bid = blockIdx.x;
  int xcd = bid & 7, loc = bid >> 3;
  int b = xcd * 16 + (loc >> 1);
  int lh = loc & 1;
  const int Poff = 81920, RMAX = 114688, RSUM = 115712;

  // ---- scores A staging ----
  int arow = (w & 3) * 16 + (l >> 2);
  int achk = (l & 3) ^ ((arow >> 1) & 3);
  const unsigned short* aW = (w < 4) ? QWh : QWl;
  const unsigned short* asrc = aW + (size_t)(lh * 64 + arow) * 1024 + achk * 8;
  int aOff = ((w < 4) ? 0 : 4096) + (w & 3) * 1024;
  // ---- scores B staging (coalesced): 8 lanes/row, 4 row-slots/thread ----
  int bR0 = tid >> 3;                       // rows bR0 + {0,64,128,192}
  int bc  = (tid >> 1) & 3;                 // 16-B chunk index in 64-B bf16 row
  // (R>>1)&3 identical for R, R+64, R+128, R+192 -> one swizzled offset + s*4096
  int bb0 = bR0 * 64 + ((bc ^ ((bR0 >> 1) & 3)) << 4) + (tid & 1) * 8;
  const float* gB0 = img + ((size_t)b * 256 + bR0) * 1024 + (tid & 7) * 4;

  char* scur = &lds[0];
  char* snxt = &lds[40960];
  char* snx2 = &lds[81920];
  f32x4 vA0, vA1, vA2, vA3, vB0, vB1, vB2, vB3;
  f32x4 acc[2][4] = {};

#define SC_LOADB(K0, R0, R1, R2, R3) { \
    R0 = *(const f32x4*)(gB0 + (K0)); \
    R1 = *(const f32x4*)(gB0 + 65536 + (K0)); \
    R2 = *(const f32x4*)(gB0 + 131072 + (K0)); \
    R3 = *(const f32x4*)(gB0 + 196608 + (K0)); }

#define SC_CONV1(DST, V, S) { \
    unsigned h0 = cvtpk((V)[0], (V)[1]), h1 = cvtpk((V)[2], (V)[3]); \
    unsigned q0 = cvtpk((V)[0] - bflo_f(h0), (V)[1] - bfhi_f(h0)); \
    unsigned q1 = cvtpk((V)[2] - bflo_f(h1), (V)[3] - bfhi_f(h1)); \
    u32x2 hv = {h0, h1}, lv = {q0, q1}; \
    *(u32x2*)((DST) + 8192 + bb0 + (S) * 4096) = hv; \
    *(u32x2*)((DST) + 24576 + bb0 + (S) * 4096) = lv; }

#define SC_CONV(DST, V0, V1, V2, V3) { \
    SC_CONV1(DST, V0, 0); \
    SC_CONV1(DST, V1, 1); \
    SC_CONV1(DST, V2, 2); \
    SC_CONV1(DST, V3, 3); }

#define SC_COMPUTE(BUF) { \
    s16x8 ah[2], al2[2], bh[4], bl[4]; \
    _Pragma("unroll") \
    for (int i = 0; i < 2; i++) { \
      int row = wm * 32 + i * 16 + lr; \
      int byte = row * 64 + ((lk8 ^ sF) << 4); \
      ah[i] = *(const s16x8*)((BUF) + byte); \
      al2[i] = *(const s16x8*)((BUF) + 4096 + byte); \
    } \
    _Pragma("unroll") \
    for (int j = 0; j < 4; j++) { \
      int n = wn * 64 + j * 16 + lr; \
      int byte = n * 64 + ((lk8 ^ sF) << 4); \
      bh[j] = *(const s16x8*)((BUF) + 8192 + byte); \
      bl[j] = *(const s16x8*)((BUF) + 24576 + byte); \
    } \
    __builtin_amdgcn_s_setprio(1); \
    _Pragma("unroll") \
    for (int i = 0; i < 2; i++) \
      _Pragma("unroll") \
      for (int j = 0; j < 4; j++) { \
        acc[i][j] = __builtin_amdgcn_mfma_f32_16x16x32_bf16(ah[i], bh[j], acc[i][j], 0, 0, 0); \
        acc[i][j] = __builtin_amdgcn_mfma_f32_16x16x32_bf16(ah[i], bl[j], acc[i][j], 0, 0, 0); \
        acc[i][j] = __builtin_amdgcn_mfma_f32_16x16x32_bf16(al2[i], bh[j], acc[i][j], 0, 0, 0); \
      } \
    __builtin_amdgcn_s_setprio(0); }

#define SC_STEP(T, CI0, CI1, CI2, CI3, CO0, CO1, CO2, CO3) { \
    int kn = ((T) + 2) * 32; \
    SC_LOADB(kn, CO0, CO1, CO2, CO3); \
    SFENCE(); \
    gload_lds16(asrc + kn, snx2 + aOff); \
    SFENCE(); \
    SC_COMPUTE(scur); \
    SC_CONV(snxt, CI0, CI1, CI2, CI3); \
    VMCNT(5); \
    LGKM0(); \
    SBAR(); \
    SFENCE(); \
    { char* t_ = scur; scur = snxt; snxt = snx2; snx2 = t_; } }

  // prologue: tiles 0,1
  SC_LOADB(0, vA0, vA1, vA2, vA3);
  SFENCE();
  gload_lds16(asrc, scur + aOff);
  SFENCE();
  SC_LOADB(32, vB0, vB1, vB2, vB3);
  SFENCE();
  gload_lds16(asrc + 32, snxt + aOff);
  SFENCE();
  SC_CONV(scur, vA0, vA1, vA2, vA3);
  VMCNT(5);
  LGKM0();
  SBAR();
  SFENCE();
#pragma unroll 1
  for (int it = 0; it < 15; ++it) {
    SC_STEP(2 * it,     vB0, vB1, vB2, vB3, vA0, vA1, vA2, vA3);
    SC_STEP(2 * it + 1, vA0, vA1, vA2, vA3, vB0, vB1, vB2, vB3);
  }
  // step 30: compute + write B(31), drain
  SC_COMPUTE(scur);
  SC_CONV(snxt, vB0, vB1, vB2, vB3);
  VMCNT(0);
  LGKM0();
  SBAR();
  SFENCE();
  { char* t_ = scur; scur = snxt; snxt = snx2; snx2 = t_; }
  // step 31
  SC_COMPUTE(scur);
  SBAR();
  SFENCE();
#undef SC_STEP
#undef SC_COMPUTE
#undef SC_CONV
#undef SC_CONV1
#undef SC_LOADB

  // ---- softmax over r=256 (rows = caption l), in-register + LDS reduce ----
  {
#pragma unroll
    for (int i = 0; i < 2; i++)
#pragma unroll
      for (int q = 0; q < 4; q++) {
        float m = fmaxf(fmaxf(acc[i][0][q], acc[i][1][q]),
                        fmaxf(acc[i][2][q], acc[i][3][q]));
#pragma unroll
        for (int s = 1; s < 16; s <<= 1) m = fmaxf(m, __shfl_xor(m, s, 64));
        if (lr == 0)
          *(float*)(lds + RMAX + (wm * 32 + i * 16 + rh + q) * 16 + wn * 4) = m;
      }
    LGKM0();
    SBAR();
#pragma unroll
    for (int i = 0; i < 2; i++)
#pragma unroll
      for (int q = 0; q < 4; q++) {
        int row = wm * 32 + i * 16 + rh + q;
        const float* rm = (const float*)(lds + RMAX + row * 16);
        float g = fmaxf(fmaxf(rm[0], rm[1]), fmaxf(rm[2], rm[3]));
        float ps = 0.f;
#pragma unroll
        for (int j = 0; j < 4; j++) {
          float e = __expf(acc[i][j][q] - g);
          acc[i][j][q] = e;
          ps += e;
        }
#pragma unroll
        for (int s = 1; s < 16; s <<= 1) ps += __shfl_xor(ps, s, 64);
        if (lr == 0) *(float*)(lds + RSUM + row * 16 + wn * 4) = ps;
      }
    LGKM0();
    SBAR();
#pragma unroll
    for (int i = 0; i < 2; i++)
#pragma unroll
      for (int q = 0; q < 4; q++) {
        int row = wm * 32 + i * 16 + rh + q;
        const float* rs = (const float*)(lds + RSUM + row * 16);
        float sc = 0.03125f / (rs[0] + rs[1] + rs[2] + rs[3]);
#pragma unroll
        for (int j = 0; j < 4; j++) {
          int col = wn * 64 + j * 16 + lr;
          int byte = Poff + row * 512 +
                     (((col >> 3) ^ ((row & 7) << 2)) << 4) + (col & 7) * 2;
          *(unsigned short*)(lds + byte) = f2bf(acc[i][j][q] * sc);
        }
      }
    LGKM0();
    SBAR();
    SFENCE();
  }

  // ---- ctx phase: ctx[64 l][1024 d] = P @ img[b], 32 steps (4 d-chunks x 8 k) ----
  {
    int u = tid & 15, dc = tid >> 4;        // u: r-pair, dc: 8-d group (0..31)
    const float* gva = img + ((size_t)b * 256 + 2 * u) * 1024 + dc * 8;
    const float* gvb = gva + 1024;
    char* ccur = &lds[0];
    char* cnxt = &lds[16384];
    char* cnx2 = &lds[32768];
    f32x4 vAa, vAb, vAc, vAd, vBa, vBb, vBc, vBd;
    f32x4 acc2[2][4] = {};

#define CTX_LOAD(T, Ra, Rb, Rc, Rd) { \
    int tt = ((T) < 32) ? (T) : 31; \
    size_t off = (size_t)((tt & 7) * 32) * 1024 + (tt >> 3) * 256; \
    Ra = *(const f32x4*)(gva + off); \
    Rb = *(const f32x4*)(gva + off + 4); \
    Rc = *(const f32x4*)(gvb + off); \
    Rd = *(const f32x4*)(gvb + off + 4); }

#define CTX_CONV(DST, Ra, Rb, Rc, Rd) { \
    _Pragma("unroll") \
    for (int j = 0; j < 8; j++) { \
      float x0 = (j < 4) ? (Ra)[j & 3] : (Rb)[j & 3]; \
      float x1 = (j < 4) ? (Rc)[j & 3] : (Rd)[j & 3]; \
      int dd = dc * 8 + j; \
      unsigned int w32 = cvtpk(x0, x1); \
      int byte = dd * 64 + ((4 * u) ^ (((dd >> 1) & 3) << 4)); \
      *(unsigned int*)((DST) + byte) = w32; \
    } }

#define CTX_STEP(T, CIa, CIb, CIc, CId, COa, COb, COc, COd) { \
    CTX_LOAD((T) + 2, COa, COb, COc, COd); \
    SFENCE(); \
    s16x8 af[2], bf[4]; \
    _Pragma("unroll") \
    for (int i = 0; i < 2; i++) { \
      int row = wm * 32 + i * 16 + lr; \
      int rc = ((T) & 7) * 4 + lk8; \
      int byte = Poff + row * 512 + ((rc ^ ((row & 7) << 2)) << 4); \
      af[i] = *(const s16x8*)(lds + byte); \
    } \
    _Pragma("unroll") \
    for (int j = 0; j < 4; j++) { \
      int n = wn * 64 + j * 16 + lr; \
      int byte = n * 64 + ((lk8 ^ ((n >> 1) & 3)) << 4); \
      bf[j] = *(const s16x8*)(ccur + byte); \
    } \
    __builtin_amdgcn_s_setprio(1); \
    _Pragma("unroll") \
    for (int i = 0; i < 2; i++) \
      _Pragma("unroll") \
      for (int j = 0; j < 4; j++) \
        acc2[i][j] = __builtin_amdgcn_mfma_f32_16x16x32_bf16(af[i], bf[j], acc2[i][j], 0, 0, 0); \
    __builtin_amdgcn_s_setprio(0); \
    CTX_CONV(cnxt, CIa, CIb, CIc, CId); \
    if (((T) & 7) == 7) { \
      int d0c = ((T) >> 3) * 256; \
      _Pragma("unroll") \
      for (int i = 0; i < 2; i++) \
        _Pragma("unroll") \
        for (int q = 0; q < 4; q++) { \
          int gl = lh * 64 + wm * 32 + i * 16 + rh + q; \
          _Pragma("unroll") \
          for (int j = 0; j < 4; j++) { \
            int gn = d0c + wn * 64 + j * 16 + lr; \
            Cp[((size_t)b * 128 + gl) * 1024 + gn] = f2bf(acc2[i][j][q]); \
            acc2[i][j][q] = 0.f; \
          } \
        } \
    } \
    VMCNT(4); \
    LGKM0(); \
    SBAR(); \
    SFENCE(); \
    { char* t_ = ccur; ccur = cnxt; cnxt = cnx2; cnx2 = t_; } }

    CTX_LOAD(0, vAa, vAb, vAc, vAd);
    SFENCE();
    CTX_LOAD(1, vBa, vBb, vBc, vBd);
    SFENCE();
    CTX_CONV(ccur, vAa, vAb, vAc, vAd);
    VMCNT(4);
    LGKM0();
    SBAR();
    SFENCE();
#pragma unroll 1
    for (int it = 0; it < 16; ++it) {
      int t0 = 2 * it;
      CTX_STEP(t0,     vBa, vBb, vBc, vBd, vAa, vAb, vAc, vAd);
      CTX_STEP(t0 + 1, vAa, vAb, vAc, vAd, vBa, vBb, vBc, vBd);
    }
#undef CTX_STEP
#undef CTX_CONV
#undef CTX_LOAD
  }
}

// ---------------- K10: out[m][n] = sum_k ctx[m][k]*Wv[n][k] + bv[n]/32 ----------------
// 256x128 tile, 512 threads (8 waves 4x2), 3-buf counted vmcnt(3).
__global__ __launch_bounds__(512, 2) void k_gemm_out(
    const unsigned short* __restrict__ A, const unsigned short* __restrict__ Bm,
    const float* __restrict__ bv, float* __restrict__ Out) {
  __shared__ __attribute__((aligned(16))) char lds[73728];
  int tid = threadIdx.x, l = tid & 63, w = tid >> 6;   // 8 waves
  int wm = w >> 1, wn = w & 1;                          // 4 x 2
  int rid = blockIdx.x;
  int xcd = rid & 7, lid = rid >> 3;
  int bm = (xcd * 8 + (lid >> 3)) * 256;
  int bn = (lid & 7) * 128;
  int lr = l & 15, lk8 = l >> 4;
  int sF = (lr >> 1) & 3;
  int srow = tid >> 2;                      // 0..127
  int swz = (tid & 3) ^ ((tid >> 3) & 3);
  const unsigned short* a0 = A + (size_t)(bm + srow) * 1024 + swz * 8;
  const unsigned short* a1 = A + (size_t)(bm + 128 + srow) * 1024 + swz * 8;
  const unsigned short* b0 = Bm + (size_t)(bn + srow) * 1024 + swz * 8;
  char* cur = &lds[0];
  char* nxt = &lds[24576];
  char* nx2 = &lds[49152];
  f32x4 acc[4][4] = {};

#define OUT_STAGE(KN, BUF) { \
    gload_lds16(a0 + (KN), (BUF) + w * 1024); \
    gload_lds16(a1 + (KN), (BUF) + 8192 + w * 1024); \
    gload_lds16(b0 + (KN), (BUF) + 16384 + w * 1024); }

#define OUT_STEP(T) { \
    int kn = (((T) + 2 < 32) ? (T) + 2 : 31) * 32; \
    OUT_STAGE(kn, nx2); \
    SFENCE(); \
    s16x8 af[4], bf[4]; \
    _Pragma("unroll") \
    for (int i = 0; i < 4; i++) { \
      int byte = (wm * 64 + i * 16 + lr) * 64 + ((lk8 ^ sF) << 4); \
      af[i] = *(const s16x8*)(cur + byte); \
    } \
    _Pragma("unroll") \
    for (int i = 0; i < 4; i++) { \
      int byte = 16384 + (wn * 64 + i * 16 + lr) * 64 + ((lk8 ^ sF) << 4); \
      bf[i] = *(const s16x8*)(cur + byte); \
    } \
    __builtin_amdgcn_s_setprio(1); \
    _Pragma("unroll") \
    for (int i = 0; i < 4; i++) \
      _Pragma("unroll") \
      for (int j = 0; j < 4; j++) \
        acc[i][j] = __builtin_amdgcn_mfma_f32_16x16x32_bf16(af[i], bf[j], acc[i][j], 0, 0, 0); \
    __builtin_amdgcn_s_setprio(0); \
    VMCNT(3); \
    SBAR(); \
    SFENCE(); \
    { char* t_ = cur; cur = nxt; nxt = nx2; nx2 = t_; } }

  OUT_STAGE(0, cur);
  SFENCE();
  OUT_STAGE(32, nxt);
  SFENCE();
  VMCNT(3);
  SBAR();
  SFENCE();

#pragma unroll 1
  for (int t = 0; t < 32; ++t) {
    OUT_STEP(t);
  }

  int rh = (l >> 4) * 4;
#pragma unroll
  for (int i = 0; i < 4; i++)
#pragma unroll
    for (int q = 0; q < 4; q++) {
      int gm = bm + wm * 64 + i * 16 + rh + q;
#pragma unroll
      for (int j = 0; j < 4; j++) {
        int gn = bn + wn * 64 + j * 16 + lr;
        Out[(size_t)gm * 1024 + gn] = acc[i][j][q] + 0.03125f * bv[gn];
      }
    }
#undef OUT_STEP
#undef OUT_STAGE
}

extern "C" void kernel_launch(void* const* d_in, const int* in_sizes, int n_in,
                              void* d_out, int out_size, void* d_ws, size_t ws_size,
                              hipStream_t stream) {
  const float* cap = (const float*)d_in[0];
  const float* img = (const float*)d_in[1];
  const float* Wq  = (const float*)d_in[2];
  const float* bq  = (const float*)d_in[3];
  const float* Wk  = (const float*)d_in[4];
  // d_in[5] = bk: constant across r -> cancels in softmax. Unused.
  const float* Wv  = (const float*)d_in[6];
  const float* bv  = (const float*)d_in[7];
  float* out = (float*)d_out;

  char* ws = (char*)d_ws;
  if (ws_size < 40370176ull) return;  // fail loudly (output stays poisoned)
  unsigned short* ctx = (unsigned short*)(ws);               // 32 MB
  float*          Qp  = (float*)(ws + 33554432);             //  2 MB (4 K-partials)
  float*          QWp = (float*)(ws + 35651584);             //  2 MB (4 K-partials)
  unsigned short* QWh = (unsigned short*)(ws + 37748736);    // 256 KB
  unsigned short* QWl = (unsigned short*)(ws + 38010880);    // 256 KB
  unsigned short* Wvh = (unsigned short*)(ws + 38273024);    //   2 MB

  // Q partials = cap @ Wq^T  (f32 TN, K-split 4, 512 blocks x 8 steps)
  k_q_part<<<dim3(4, 32, 4), 256, 0, stream>>>(cap, Wq, Qp);
  // QW partials = (sum Qp + bq) @ Wk  (f32 NN, K-split 4)
  k_qw_part<<<dim3(4, 32, 4), 256, 0, stream>>>(Qp, bq, Wk, QWp);
  // QWh/QWl = split(sum QWp); Wvh = bf16(Wv)  (one launch)
  k_reduce_convert<<<1152, 256, 0, stream>>>(QWp, Wv, QWh, QWl, Wvh);
  // fused: scores (3-pass split bf16, coalesced B-staging) + softmax/32 + ctx
  k_fused<<<256, 512, 0, stream>>>(QWh, QWl, img, ctx);
  // out = ctx @ Wv^T + bv/32  (256x128 counted-vmcnt pipeline)
  k_gemm_out<<<512, 512, 0, stream>>>(ctx, Wvh, bv, out);
}

// Round 18
// 154.494 us; speedup vs baseline: 1.0239x; 1.0239x over previous
//
#include <hip/hip_runtime.h>
#include <stdint.h>

typedef __attribute__((ext_vector_type(4))) float  f32x4;
typedef __attribute__((ext_vector_type(8))) short  s16x8;
typedef __attribute__((ext_vector_type(4))) short  s16x4;
typedef __attribute__((ext_vector_type(4))) unsigned int u32x4;
typedef __attribute__((ext_vector_type(2))) unsigned int u32x2;

__device__ __forceinline__ unsigned short f2bf(float x) {
  union { float f; unsigned int u; } a; a.f = x;
  unsigned int lsb = (a.u >> 16) & 1u;
  a.u += 0x7fffu + lsb;                    // round-to-nearest-even
  return (unsigned short)(a.u >> 16);
}
__device__ __forceinline__ float bf2f(unsigned short h) {
  union { unsigned int u; float f; } a; a.u = ((unsigned int)h) << 16; return a.f;
}
// HW packed f32->bf16 RNE: lo16 = bf16(a), hi16 = bf16(b). Bit-identical to f2bf.
__device__ __forceinline__ unsigned int cvtpk(float a, float b) {
  unsigned int d;
  asm("v_cvt_pk_bf16_f32 %0, %1, %2" : "=v"(d) : "v"(a), "v"(b));
  return d;
}
__device__ __forceinline__ float bflo_f(unsigned int u) {
  union { unsigned int u; float f; } x; x.u = u << 16; return x.f;
}
__device__ __forceinline__ float bfhi_f(unsigned int u) {
  union { unsigned int u; float f; } x; x.u = u & 0xffff0000u; return x.f;
}
__device__ __forceinline__ s16x8 pk4(unsigned a, unsigned b, unsigned c, unsigned d) {
  union { u32x4 u; s16x8 s; } x;
  u32x4 v = {a, b, c, d}; x.u = v; return x.s;
}

__device__ __forceinline__ void gload_lds16(const void* g, void* s) {
  __builtin_amdgcn_global_load_lds(
      (__attribute__((address_space(1))) void*)g,
      (__attribute__((address_space(3))) void*)s, 16, 0, 0);
}

#define VMCNT(N) asm volatile("s_waitcnt vmcnt(" #N ")" ::: "memory")
#define LGKM0()  asm volatile("s_waitcnt lgkmcnt(0)" ::: "memory")
#define SBAR()   __builtin_amdgcn_s_barrier()
#define SFENCE() __builtin_amdgcn_sched_barrier(0)

// ---------------- K1: Q partials (f32 TN, K-split 4) ----------------
__global__ __launch_bounds__(256) void k_q_part(
    const float* __restrict__ A, const float* __restrict__ Bm,
    float* __restrict__ Qp) {
  __shared__ float As[32][33], Bs[32][33];
  int tid = threadIdx.x;
  int bm = blockIdx.x * 32, bn = blockIdx.y * 32;
  int kbase = blockIdx.z * 256;
  int tr = tid & 31, tq = tid >> 5;
  float acc[4] = {0.f, 0.f, 0.f, 0.f};
  for (int k0 = kbase; k0 < kbase + 256; k0 += 32) {
#pragma unroll
    for (int i = 0; i < 4; i++) {
      int idx = tid + i * 256;
      int r = idx >> 5, c = idx & 31;
      As[r][c] = A[(size_t)(bm + r) * 1024 + k0 + c];
      Bs[r][c] = Bm[(size_t)(bn + r) * 1024 + k0 + c];
    }
    __syncthreads();
#pragma unroll
    for (int kk = 0; kk < 32; kk++) {
      float b = Bs[tr][kk];
#pragma unroll
      for (int i = 0; i < 4; i++) acc[i] += As[tq * 4 + i][kk] * b;
    }
    __syncthreads();
  }
#pragma unroll
  for (int i = 0; i < 4; i++)
    Qp[(size_t)blockIdx.z * 131072 + (size_t)(bm + tq * 4 + i) * 1024 + bn + tr] = acc[i];
}

// ---------------- K2: QW partials (f32 NN, K-split 4) ----------------
__global__ __launch_bounds__(256) void k_qw_part(
    const float* __restrict__ Qp, const float* __restrict__ bq,
    const float* __restrict__ Wk, float* __restrict__ QWp) {
  __shared__ float As[32][33], Bs[32][33];
  int tid = threadIdx.x;
  int bm = blockIdx.x * 32, bn = blockIdx.y * 32;
  int kbase = blockIdx.z * 256;
  int tr = tid & 31, tq = tid >> 5;
  float acc[4] = {0.f, 0.f, 0.f, 0.f};
  for (int k0 = kbase; k0 < kbase + 256; k0 += 32) {
#pragma unroll
    for (int i = 0; i < 4; i++) {
      int idx = tid + i * 256;
      int r = idx >> 5, c = idx & 31;
      size_t qa = (size_t)(bm + r) * 1024 + k0 + c;
      float s = (Qp[qa] + Qp[qa + 131072]) + (Qp[qa + 262144] + Qp[qa + 393216]);
      As[r][c] = s + bq[k0 + c];
      Bs[r][c] = Wk[(size_t)(k0 + r) * 1024 + bn + c];
    }
    __syncthreads();
#pragma unroll
    for (int kk = 0; kk < 32; kk++) {
      float b = Bs[kk][tr];
#pragma unroll
      for (int i = 0; i < 4; i++) acc[i] += As[tq * 4 + i][kk] * b;
    }
    __syncthreads();
  }
#pragma unroll
  for (int i = 0; i < 4; i++)
    QWp[(size_t)blockIdx.z * 131072 + (size_t)(bm + tq * 4 + i) * 1024 + bn + tr] = acc[i];
}

// ---------------- K3: reduce QW partials -> hi/lo split; + convert Wv -> bf16 ----------------
__global__ __launch_bounds__(256) void k_reduce_convert(
    const float* __restrict__ QWp, const float* __restrict__ Wv,
    unsigned short* __restrict__ QWh, unsigned short* __restrict__ QWl,
    unsigned short* __restrict__ Wvh) {
  int bid = blockIdx.x;
  if (bid < 128) {
    int i = bid * 256 + threadIdx.x;        // f32x4 index, 32768 total
    const f32x4* P4 = (const f32x4*)QWp;
    f32x4 a = P4[i], b = P4[i + 32768], c = P4[i + 65536], d = P4[i + 98304];
    f32x4 s;
#pragma unroll
    for (int j = 0; j < 4; j++) s[j] = (a[j] + b[j]) + (c[j] + d[j]);
    unsigned h0 = cvtpk(s[0], s[1]), h1 = cvtpk(s[2], s[3]);
    unsigned l0 = cvtpk(s[0] - bflo_f(h0), s[1] - bfhi_f(h0));
    unsigned l1 = cvtpk(s[2] - bflo_f(h1), s[3] - bfhi_f(h1));
    u32x2 hv = {h0, h1}, lv = {l0, l1};
    ((u32x2*)QWh)[i] = hv;
    ((u32x2*)QWl)[i] = lv;
  } else {
    int i = (bid - 128) * 256 + threadIdx.x;  // f32x4 index, 262144 total
    f32x4 v = ((const f32x4*)Wv)[i];
    u32x2 h;
    h[0] = cvtpk(v[0], v[1]);
    h[1] = cvtpk(v[2], v[3]);
    ((u32x2*)Wvh)[i] = h;
  }
}

// ---------------- K5: fused scores + softmax + ctx ----------------
// Block (b, lh): scores S[64 l][256 r] = QW[lh] @ img[b]^T. Depth-3 register
// pipeline: conv(t+1) uses regs loaded at t-2 (2-step cover); VMCNT(9) leaves
// 10 VMEM in flight across each barrier. Then in-register softmax; P ->
// swizzled LDS; ctx = P @ img[b] (depth-3 reg pipeline, transpose-staged).
__global__ __launch_bounds__(512, 2) void k_fused(
    const unsigned short* __restrict__ QWh, const unsigned short* __restrict__ QWl,
    const float* __restrict__ img, unsigned short* __restrict__ Cp) {
  // bufs 0/40960/81920, each 40 KB: Ah@0 (4K), Al@4096 (4K), Bh@8192 (16K),
  // Bl@24576 (16K). After scores: P@81920 (32K), RMAX@114688, RSUM@115712.
  // ctx bufs 0/16384/32768 (16 KB each) live in buf0/buf1 space.
  __shared__ __attribute__((aligned(16))) char lds[122880];
  int tid = threadIdx.x, l = tid & 63, w = tid >> 6;
  int wm = w >> 2, wn = w & 3;              // 2 x 4 wave grid
  int lr = l & 15, lk8 = l >> 4;
  int sF = (lr >> 1) & 3;
  int rh = lk8 * 4;
  int bid = blockIdx.x;
  int xcd = bid & 7, loc = bid >> 3;
  int b = xcd * 16 + (loc >> 1);
  int lh = loc & 1;
  const int Poff = 81920, RMAX = 114688, RSUM = 115712;

  // ---- scores A staging ----
  int arow = (w & 3) * 16 + (l >> 2);
  int achk = (l & 3) ^ ((arow >> 1) & 3);
  const unsigned short* aW = (w < 4) ? QWh : QWl;
  const unsigned short* asrc = aW + (size_t)(lh * 64 + arow) * 1024 + achk * 8;
  int aOff = ((w < 4) ? 0 : 4096) + (w & 3) * 1024;
  // ---- scores B staging (coalesced): 8 lanes/row, 4 row-slots/thread ----
  int bR0 = tid >> 3;                       // rows bR0 + {0,64,128,192}
  int bc  = (tid >> 1) & 3;                 // 16-B chunk index in 64-B bf16 row
  int bb0 = bR0 * 64 + ((bc ^ ((bR0 >> 1) & 3)) << 4) + (tid & 1) * 8;
  const float* gB0 = img + ((size_t)b * 256 + bR0) * 1024 + (tid & 7) * 4;

  char* scur = &lds[0];
  char* snxt = &lds[40960];
  char* snx2 = &lds[81920];
  f32x4 sA0, sA1, sA2, sA3, sB0, sB1, sB2, sB3, sC0, sC1, sC2, sC3;
  f32x4 acc[2][4] = {};

#define SC_LOADB(K0, R0, R1, R2, R3) { \
    R0 = *(const f32x4*)(gB0 + (K0)); \
    R1 = *(const f32x4*)(gB0 + 65536 + (K0)); \
    R2 = *(const f32x4*)(gB0 + 131072 + (K0)); \
    R3 = *(const f32x4*)(gB0 + 196608 + (K0)); }

#define SC_CONV1(DST, V, S) { \
    unsigned h0 = cvtpk((V)[0], (V)[1]), h1 = cvtpk((V)[2], (V)[3]); \
    unsigned q0 = cvtpk((V)[0] - bflo_f(h0), (V)[1] - bfhi_f(h0)); \
    unsigned q1 = cvtpk((V)[2] - bflo_f(h1), (V)[3] - bfhi_f(h1)); \
    u32x2 hv = {h0, h1}, lv = {q0, q1}; \
    *(u32x2*)((DST) + 8192 + bb0 + (S) * 4096) = hv; \
    *(u32x2*)((DST) + 24576 + bb0 + (S) * 4096) = lv; }

#define SC_CONV(DST, V0, V1, V2, V3) { \
    SC_CONV1(DST, V0, 0); \
    SC_CONV1(DST, V1, 1); \
    SC_CONV1(DST, V2, 2); \
    SC_CONV1(DST, V3, 3); }

#define SC_COMPUTE(BUF) { \
    s16x8 ah[2], al2[2], bh[4], bl[4]; \
    _Pragma("unroll") \
    for (int i = 0; i < 2; i++) { \
      int row = wm * 32 + i * 16 + lr; \
      int byte = row * 64 + ((lk8 ^ sF) << 4); \
      ah[i] = *(const s16x8*)((BUF) + byte); \
      al2[i] = *(const s16x8*)((BUF) + 4096 + byte); \
    } \
    _Pragma("unroll") \
    for (int j = 0; j < 4; j++) { \
      int n = wn * 64 + j * 16 + lr; \
      int byte = n * 64 + ((lk8 ^ sF) << 4); \
      bh[j] = *(const s16x8*)((BUF) + 8192 + byte); \
      bl[j] = *(const s16x8*)((BUF) + 24576 + byte); \
    } \
    __builtin_amdgcn_s_setprio(1); \
    _Pragma("unroll") \
    for (int i = 0; i < 2; i++) \
      _Pragma("unroll") \
      for (int j = 0; j < 4; j++) { \
        acc[i][j] = __builtin_amdgcn_mfma_f32_16x16x32_bf16(ah[i], bh[j], acc[i][j], 0, 0, 0); \
        acc[i][j] = __builtin_amdgcn_mfma_f32_16x16x32_bf16(ah[i], bl[j], acc[i][j], 0, 0, 0); \
        acc[i][j] = __builtin_amdgcn_mfma_f32_16x16x32_bf16(al2[i], bh[j], acc[i][j], 0, 0, 0); \
      } \
    __builtin_amdgcn_s_setprio(0); }

// Step t: issue A-gload(t+2) then B-regs(t+3); compute(t); conv(t+1) from
// regs loaded at t-2 (auto-waited, 2-step cover); VMCNT(9) drains A(t+1).
#define SC_STEP(T, C0, C1, C2, C3, L0, L1, L2, L3) { \
    int ka = ((T) + 2) * 32; \
    int kb = (((T) + 3 < 32) ? (T) + 3 : 31) * 32; \
    gload_lds16(asrc + ka, snx2 + aOff); \
    SFENCE(); \
    SC_LOADB(kb, L0, L1, L2, L3); \
    SFENCE(); \
    SC_COMPUTE(scur); \
    SC_CONV(snxt, C0, C1, C2, C3); \
    VMCNT(9); \
    LGKM0(); \
    SBAR(); \
    SFENCE(); \
    { char* t_ = scur; scur = snxt; snxt = snx2; snx2 = t_; } }

  // prologue: A(0),B(0); A(1),B(1); B(2); conv B(0)
  gload_lds16(asrc, scur + aOff);
  SFENCE();
  SC_LOADB(0, sA0, sA1, sA2, sA3);
  SFENCE();
  gload_lds16(asrc + 32, snxt + aOff);
  SFENCE();
  SC_LOADB(32, sB0, sB1, sB2, sB3);
  SFENCE();
  SC_LOADB(64, sC0, sC1, sC2, sC3);
  SFENCE();
  SC_CONV(scur, sA0, sA1, sA2, sA3);
  LGKM0();
  SBAR();
  SFENCE();
#pragma unroll 1
  for (int t3 = 0; t3 < 30; t3 += 3) {
    SC_STEP(t3,     sB0, sB1, sB2, sB3, sA0, sA1, sA2, sA3);
    SC_STEP(t3 + 1, sC0, sC1, sC2, sC3, sB0, sB1, sB2, sB3);
    SC_STEP(t3 + 2, sA0, sA1, sA2, sA3, sC0, sC1, sC2, sC3);
  }
  // step 30: compute + conv(31) (regs loaded at t=28 -> sB), drain
  SC_COMPUTE(scur);
  SC_CONV(snxt, sB0, sB1, sB2, sB3);
  VMCNT(0);
  LGKM0();
  SBAR();
  SFENCE();
  { char* t_ = scur; scur = snxt; snxt = snx2; snx2 = t_; }
  // step 31
  SC_COMPUTE(scur);
  SBAR();
  SFENCE();
#undef SC_STEP
#undef SC_COMPUTE
#undef SC_CONV
#undef SC_CONV1
#undef SC_LOADB

  // ---- softmax over r=256 (rows = caption l), in-register + LDS reduce ----
  {
#pragma unroll
    for (int i = 0; i < 2; i++)
#pragma unroll
      for (int q = 0; q < 4; q++) {
        float m = fmaxf(fmaxf(acc[i][0][q], acc[i][1][q]),
                        fmaxf(acc[i][2][q], acc[i][3][q]));
#pragma unroll
        for (int s = 1; s < 16; s <<= 1) m = fmaxf(m, __shfl_xor(m, s, 64));
        if (lr == 0)
          *(float*)(lds + RMAX + (wm * 32 + i * 16 + rh + q) * 16 + wn * 4) = m;
      }
    LGKM0();
    SBAR();
#pragma unroll
    for (int i = 0; i < 2; i++)
#pragma unroll
      for (int q = 0; q < 4; q++) {
        int row = wm * 32 + i * 16 + rh + q;
        const float* rm = (const float*)(lds + RMAX + row * 16);
        float g = fmaxf(fmaxf(rm[0], rm[1]), fmaxf(rm[2], rm[3]));
        float ps = 0.f;
#pragma unroll
        for (int j = 0; j < 4; j++) {
          float e = __expf(acc[i][j][q] - g);
          acc[i][j][q] = e;
          ps += e;
        }
#pragma unroll
        for (int s = 1; s < 16; s <<= 1) ps += __shfl_xor(ps, s, 64);
        if (lr == 0) *(float*)(lds + RSUM + row * 16 + wn * 4) = ps;
      }
    LGKM0();
    SBAR();
#pragma unroll
    for (int i = 0; i < 2; i++)
#pragma unroll
      for (int q = 0; q < 4; q++) {
        int row = wm * 32 + i * 16 + rh + q;
        const float* rs = (const float*)(lds + RSUM + row * 16);
        float sc = 0.03125f / (rs[0] + rs[1] + rs[2] + rs[3]);
#pragma unroll
        for (int j = 0; j < 4; j++) {
          int col = wn * 64 + j * 16 + lr;
          int byte = Poff + row * 512 +
                     (((col >> 3) ^ ((row & 7) << 2)) << 4) + (col & 7) * 2;
          *(unsigned short*)(lds + byte) = f2bf(acc[i][j][q] * sc);
        }
      }
    LGKM0();
    SBAR();
    SFENCE();
  }

  // ---- ctx phase: ctx[64 l][1024 d] = P @ img[b], 32 steps, depth-3 regs ----
  {
    int u = tid & 15, dc = tid >> 4;        // u: r-pair, dc: 8-d group (0..31)
    const float* gva = img + ((size_t)b * 256 + 2 * u) * 1024 + dc * 8;
    const float* gvb = gva + 1024;
    char* ccur = &lds[0];
    char* cnxt = &lds[16384];
    char* cnx2 = &lds[32768];
    f32x4 cAa, cAb, cAc, cAd, cBa, cBb, cBc, cBd, cCa, cCb, cCc, cCd;
    f32x4 acc2[2][4] = {};

#define CTX_LOAD(T, Ra, Rb, Rc, Rd) { \
    int tt = ((T) < 32) ? (T) : 31; \
    size_t off = (size_t)((tt & 7) * 32) * 1024 + (tt >> 3) * 256; \
    Ra = *(const f32x4*)(gva + off); \
    Rb = *(const f32x4*)(gva + off + 4); \
    Rc = *(const f32x4*)(gvb + off); \
    Rd = *(const f32x4*)(gvb + off + 4); }

#define CTX_CONV(DST, Ra, Rb, Rc, Rd) { \
    _Pragma("unroll") \
    for (int j = 0; j < 8; j++) { \
      float x0 = (j < 4) ? (Ra)[j & 3] : (Rb)[j & 3]; \
      float x1 = (j < 4) ? (Rc)[j & 3] : (Rd)[j & 3]; \
      int dd = dc * 8 + j; \
      unsigned int w32 = cvtpk(x0, x1); \
      int byte = dd * 64 + ((4 * u) ^ (((dd >> 1) & 3) << 4)); \
      *(unsigned int*)((DST) + byte) = w32; \
    } }

#define CTX_MFMA(T) { \
    s16x8 af[2], bf[4]; \
    _Pragma("unroll") \
    for (int i = 0; i < 2; i++) { \
      int row = wm * 32 + i * 16 + lr; \
      int rc = ((T) & 7) * 4 + lk8; \
      int byte = Poff + row * 512 + ((rc ^ ((row & 7) << 2)) << 4); \
      af[i] = *(const s16x8*)(lds + byte); \
    } \
    _Pragma("unroll") \
    for (int j = 0; j < 4; j++) { \
      int n = wn * 64 + j * 16 + lr; \
      int byte = n * 64 + ((lk8 ^ ((n >> 1) & 3)) << 4); \
      bf[j] = *(const s16x8*)(ccur + byte); \
    } \
    __builtin_amdgcn_s_setprio(1); \
    _Pragma("unroll") \
    for (int i = 0; i < 2; i++) \
      _Pragma("unroll") \
      for (int j = 0; j < 4; j++) \
        acc2[i][j] = __builtin_amdgcn_mfma_f32_16x16x32_bf16(af[i], bf[j], acc2[i][j], 0, 0, 0); \
    __builtin_amdgcn_s_setprio(0); }

#define CTX_STORE(T) { \
    int d0c = ((T) >> 3) * 256; \
    _Pragma("unroll") \
    for (int i = 0; i < 2; i++) \
      _Pragma("unroll") \
      for (int q = 0; q < 4; q++) { \
        int gl = lh * 64 + wm * 32 + i * 16 + rh + q; \
        _Pragma("unroll") \
        for (int j = 0; j < 4; j++) { \
          int gn = d0c + wn * 64 + j * 16 + lr; \
          Cp[((size_t)b * 128 + gl) * 1024 + gn] = f2bf(acc2[i][j][q]); \
          acc2[i][j][q] = 0.f; \
        } \
      } }

#define CTX_STEP(T, Ca, Cb, Cc, Cd, La, Lb, Lc, Ld) { \
    CTX_LOAD((T) + 3, La, Lb, Lc, Ld); \
    SFENCE(); \
    CTX_MFMA(T); \
    CTX_CONV(cnxt, Ca, Cb, Cc, Cd); \
    if (((T) & 7) == 7) CTX_STORE(T); \
    LGKM0(); \
    SBAR(); \
    SFENCE(); \
    { char* t_ = ccur; ccur = cnxt; cnxt = cnx2; cnx2 = t_; } }

    // prologue: tiles 0,1,2 into regs; conv(0)
    CTX_LOAD(0, cAa, cAb, cAc, cAd);
    SFENCE();
    CTX_LOAD(1, cBa, cBb, cBc, cBd);
    SFENCE();
    CTX_LOAD(2, cCa, cCb, cCc, cCd);
    SFENCE();
    CTX_CONV(ccur, cAa, cAb, cAc, cAd);
    LGKM0();
    SBAR();
    SFENCE();
#pragma unroll 1
    for (int t3 = 0; t3 < 30; t3 += 3) {
      CTX_STEP(t3,     cBa, cBb, cBc, cBd, cAa, cAb, cAc, cAd);
      CTX_STEP(t3 + 1, cCa, cCb, cCc, cCd, cBa, cBb, cBc, cBd);
      CTX_STEP(t3 + 2, cAa, cAb, cAc, cAd, cCa, cCb, cCc, cCd);
    }
    // step 30: compute(30), conv(31) (regs loaded at t=28 -> cB)
    CTX_MFMA(30);
    CTX_CONV(cnxt, cBa, cBb, cBc, cBd);
    LGKM0();
    SBAR();
    SFENCE();
    { char* t_ = ccur; ccur = cnxt; cnxt = cnx2; cnx2 = t_; }
    // step 31: compute + final d-chunk store
    CTX_MFMA(31);
    CTX_STORE(31);
#undef CTX_STEP
#undef CTX_STORE
#undef CTX_MFMA
#undef CTX_CONV
#undef CTX_LOAD
  }
}

// ---------------- K10: out[m][n] = sum_k ctx[m][k]*Wv[n][k] + bv[n]/32 ----------------
// 256x128 tile, 512 threads (8 waves 4x2), 3-buf counted vmcnt(3).
__global__ __launch_bounds__(512, 2) void k_gemm_out(
    const unsigned short* __restrict__ A, const unsigned short* __restrict__ Bm,
    const float* __restrict__ bv, float* __restrict__ Out) {
  __shared__ __attribute__((aligned(16))) char lds[73728];
  int tid = threadIdx.x, l = tid & 63, w = tid >> 6;   // 8 waves
  int wm = w >> 1, wn = w & 1;                          // 4 x 2
  int rid = blockIdx.x;
  int xcd = rid & 7, lid = rid >> 3;
  int bm = (xcd * 8 + (lid >> 3)) * 256;
  int bn = (lid & 7) * 128;
  int lr = l & 15, lk8 = l >> 4;
  int sF = (lr >> 1) & 3;
  int srow = tid >> 2;                      // 0..127
  int swz = (tid & 3) ^ ((tid >> 3) & 3);
  const unsigned short* a0 = A + (size_t)(bm + srow) * 1024 + swz * 8;
  const unsigned short* a1 = A + (size_t)(bm + 128 + srow) * 1024 + swz * 8;
  const unsigned short* b0 = Bm + (size_t)(bn + srow) * 1024 + swz * 8;
  char* cur = &lds[0];
  char* nxt = &lds[24576];
  char* nx2 = &lds[49152];
  f32x4 acc[4][4] = {};

#define OUT_STAGE(KN, BUF) { \
    gload_lds16(a0 + (KN), (BUF) + w * 1024); \
    gload_lds16(a1 + (KN), (BUF) + 8192 + w * 1024); \
    gload_lds16(b0 + (KN), (BUF) + 16384 + w * 1024); }

#define OUT_STEP(T) { \
    int kn = (((T) + 2 < 32) ? (T) + 2 : 31) * 32; \
    OUT_STAGE(kn, nx2); \
    SFENCE(); \
    s16x8 af[4], bf[4]; \
    _Pragma("unroll") \
    for (int i = 0; i < 4; i++) { \
      int byte = (wm * 64 + i * 16 + lr) * 64 + ((lk8 ^ sF) << 4); \
      af[i] = *(const s16x8*)(cur + byte); \
    } \
    _Pragma("unroll") \
    for (int i = 0; i < 4; i++) { \
      int byte = 16384 + (wn * 64 + i * 16 + lr) * 64 + ((lk8 ^ sF) << 4); \
      bf[i] = *(const s16x8*)(cur + byte); \
    } \
    __builtin_amdgcn_s_setprio(1); \
    _Pragma("unroll") \
    for (int i = 0; i < 4; i++) \
      _Pragma("unroll") \
      for (int j = 0; j < 4; j++) \
        acc[i][j] = __builtin_amdgcn_mfma_f32_16x16x32_bf16(af[i], bf[j], acc[i][j], 0, 0, 0); \
    __builtin_amdgcn_s_setprio(0); \
    VMCNT(3); \
    SBAR(); \
    SFENCE(); \
    { char* t_ = cur; cur = nxt; nxt = nx2; nx2 = t_; } }

  OUT_STAGE(0, cur);
  SFENCE();
  OUT_STAGE(32, nxt);
  SFENCE();
  VMCNT(3);
  SBAR();
  SFENCE();

#pragma unroll 1
  for (int t = 0; t < 32; ++t) {
    OUT_STEP(t);
  }

  int rh = (l >> 4) * 4;
#pragma unroll
  for (int i = 0; i < 4; i++)
#pragma unroll
    for (int q = 0; q < 4; q++) {
      int gm = bm + wm * 64 + i * 16 + rh + q;
#pragma unroll
      for (int j = 0; j < 4; j++) {
        int gn = bn + wn * 64 + j * 16 + lr;
        Out[(size_t)gm * 1024 + gn] = acc[i][j][q] + 0.03125f * bv[gn];
      }
    }
#undef OUT_STEP
#undef OUT_STAGE
}

extern "C" void kernel_launch(void* const* d_in, const int* in_sizes, int n_in,
                              void* d_out, int out_size, void* d_ws, size_t ws_size,
                              hipStream_t stream) {
  const float* cap = (const float*)d_in[0];
  const float* img = (const float*)d_in[1];
  const float* Wq  = (const float*)d_in[2];
  const float* bq  = (const float*)d_in[3];
  const float* Wk  = (const float*)d_in[4];
  // d_in[5] = bk: constant across r -> cancels in softmax. Unused.
  const float* Wv  = (const float*)d_in[6];
  const float* bv  = (const float*)d_in[7];
  float* out = (float*)d_out;

  char* ws = (char*)d_ws;
  if (ws_size < 40370176ull) return;  // fail loudly (output stays poisoned)
  unsigned short* ctx = (unsigned short*)(ws);               // 32 MB
  float*          Qp  = (float*)(ws + 33554432);             //  2 MB (4 K-partials)
  float*          QWp = (float*)(ws + 35651584);             //  2 MB (4 K-partials)
  unsigned short* QWh = (unsigned short*)(ws + 37748736);    // 256 KB
  unsigned short* QWl = (unsigned short*)(ws + 38010880);    // 256 KB
  unsigned short* Wvh = (unsigned short*)(ws + 38273024);    //   2 MB

  // Q partials = cap @ Wq^T  (f32 TN, K-split 4, 512 blocks x 8 steps)
  k_q_part<<<dim3(4, 32, 4), 256, 0, stream>>>(cap, Wq, Qp);
  // QW partials = (sum Qp + bq) @ Wk  (f32 NN, K-split 4)
  k_qw_part<<<dim3(4, 32, 4), 256, 0, stream>>>(Qp, bq, Wk, QWp);
  // QWh/QWl = split(sum QWp); Wvh = bf16(Wv)  (one launch)
  k_reduce_convert<<<1152, 256, 0, stream>>>(QWp, Wv, QWh, QWl, Wvh);
  // fused: scores (3-pass split bf16, depth-3 reg pipeline) + softmax/32 + ctx
  k_fused<<<256, 512, 0, stream>>>(QWh, QWl, img, ctx);
  // out = ctx @ Wv^T + bv/32  (256x128 counted-vmcnt pipeline)
  k_gemm_out<<<512, 512, 0, stream>>>(ctx, Wvh, bv, out);
}